// Round 1
// baseline (1988.211 us; speedup 1.0000x reference)
//
#include <hip/hip_runtime.h>
#include <math.h>

// BigBird block-sparse attention, fp32 vector version (correctness-first).
// B=2 H=16 M=N=4096 D=64 WM=WN=64 R=3 nb=64.
constexpr int B_  = 2;
constexpr int H_  = 16;
constexpr int M_  = 4096;
constexpr int D_  = 64;
constexpr int NB_ = 64;   // number of 64-row blocks
constexpr int R_  = 3;
constexpr float NEGV  = -10000.0f;
constexpr float SCALE = 0.125f;   // 1/sqrt(64)

// One workgroup per (b, h, q-block). 256 threads = 4 waves.
// lane (t&63) owns q-row `lane`; wave (t>>6) owns a 16-key score slice and a
// 16-dim output slice.
__global__ __launch_bounds__(256, 2)
void bigbird_fp32(const float* __restrict__ q,  const float* __restrict__ k,
                  const float* __restrict__ v,  const float* __restrict__ band_mask,
                  const float* __restrict__ from_mask, const float* __restrict__ to_mask,
                  const float* __restrict__ from_blocked, const float* __restrict__ to_blocked,
                  const int*   __restrict__ rand_attn,   float* __restrict__ out)
{
    __shared__ float k_lds[64][68];   // pad 68: 2-way write alias (free), broadcast reads
    __shared__ float v_lds[64][68];
    __shared__ float s_lds[64][66];   // pad 66: 2-way read/write alias (free)
    __shared__ int   s_kbl[64];
    __shared__ int   s_md[64];        // 0=to_mask, 1=band, 2=rand
    __shared__ int   s_boff[64];      // band column offset (0/64/128)
    __shared__ int   s_nkb;

    const int wg  = blockIdx.x;
    const int qb  = wg % NB_;
    const int h   = (wg / NB_) % H_;
    const int b   = wg / (NB_ * H_);
    const int t   = threadIdx.x;
    const int row = t & 63;
    const int wv  = t >> 6;

    // ---- build the key-block list (wave-uniform; thread 0 writes it) ----
    if (t == 0) {
        int n = 0;
        if (qb == 0 || qb == NB_ - 1) {
            for (int j = 0; j < NB_; ++j) { s_kbl[j] = j; s_md[j] = 0; s_boff[j] = 0; }
            n = NB_;
        } else {
            const int l = qb - 1;  // row into rand_attn (nb-2 rows for blocks 1..62)
            const int* ra = rand_attn + ((b * H_ + h) * (NB_ - 2) + l) * R_;
            if (qb == 1) {
                const int base[4] = {0, 1, 2, NB_ - 1};
                for (int j = 0; j < 4; ++j) { s_kbl[j] = base[j]; s_md[j] = 0; s_boff[j] = 0; }
                for (int j = 0; j < R_; ++j) { s_kbl[4 + j] = ra[j]; s_md[4 + j] = 2; s_boff[4 + j] = 0; }
                n = 4 + R_;
            } else if (qb == NB_ - 2) {
                const int base[4] = {0, NB_ - 3, NB_ - 2, NB_ - 1};
                for (int j = 0; j < 4; ++j) { s_kbl[j] = base[j]; s_md[j] = 0; s_boff[j] = 0; }
                for (int j = 0; j < R_; ++j) { s_kbl[4 + j] = ra[j]; s_md[4 + j] = 2; s_boff[4 + j] = 0; }
                n = 4 + R_;
            } else {
                s_kbl[0] = 0;      s_md[0] = 0; s_boff[0] = 0;      // firstp: to_mask[:wn]
                s_kbl[1] = qb - 1; s_md[1] = 1; s_boff[1] = 0;      // band
                s_kbl[2] = qb;     s_md[2] = 1; s_boff[2] = 64;
                s_kbl[3] = qb + 1; s_md[3] = 1; s_boff[3] = 128;
                for (int j = 0; j < R_; ++j) { s_kbl[4 + j] = ra[j]; s_md[4 + j] = 2; s_boff[4 + j] = 0; }
                s_kbl[7] = NB_ - 1; s_md[7] = 0; s_boff[7] = 0;     // lastp: to_mask[-wn:]
                n = 8;
            }
        }
        s_nkb = n;
    }

    // ---- load my q row into registers (read-only for whole kernel) ----
    const int bh = b * H_ + h;
    float qr[64];
    {
        const float* qp = q + ((size_t)bh * M_ + (size_t)qb * 64 + row) * D_;
        #pragma unroll
        for (int j4 = 0; j4 < 16; ++j4) {
            float4 qv = *(const float4*)(qp + j4 * 4);
            qr[j4 * 4 + 0] = qv.x; qr[j4 * 4 + 1] = qv.y;
            qr[j4 * 4 + 2] = qv.z; qr[j4 * 4 + 3] = qv.w;
        }
    }

    __syncthreads();
    const int nkb = s_nkb;

    const float fb = from_blocked[(b * NB_ + qb) * 64 + row];  // rand-mask row factor

    float mrun = -INFINITY, lrun = 0.0f;
    float acc[16];
    #pragma unroll
    for (int j = 0; j < 16; ++j) acc[j] = 0.0f;

    for (int it = 0; it < nkb; ++it) {
        const int kb   = s_kbl[it];
        const int mode = s_md[it];
        const int boff = s_boff[it];

        // ---- stage K/V tile (coalesced float4) ----
        {
            const float* kp = k + ((size_t)bh * M_ + (size_t)kb * 64) * D_;
            const float* vp = v + ((size_t)bh * M_ + (size_t)kb * 64) * D_;
            const int rr = t >> 2, cc = (t & 3) * 16;
            #pragma unroll
            for (int j4 = 0; j4 < 4; ++j4) {
                *(float4*)&k_lds[rr][cc + j4 * 4] = *(const float4*)(kp + rr * 64 + cc + j4 * 4);
                *(float4*)&v_lds[rr][cc + j4 * 4] = *(const float4*)(vp + rr * 64 + cc + j4 * 4);
            }
        }
        __syncthreads();

        // ---- scores: my row x keys [wv*16, wv*16+16) ----
        #pragma unroll 2
        for (int jj = 0; jj < 16; ++jj) {
            const int kk = wv * 16 + jj;
            const float4* kp4 = (const float4*)&k_lds[kk][0];   // wave-uniform -> broadcast
            float s0 = 0.f, s1 = 0.f, s2 = 0.f, s3 = 0.f;
            #pragma unroll
            for (int d4 = 0; d4 < 16; ++d4) {
                float4 kv = kp4[d4];
                s0 += qr[d4 * 4 + 0] * kv.x;
                s1 += qr[d4 * 4 + 1] * kv.y;
                s2 += qr[d4 * 4 + 2] * kv.z;
                s3 += qr[d4 * 4 + 3] * kv.w;
            }
            float s = (s0 + s1) + (s2 + s3);
            s *= SCALE;
            float mask;
            if (mode == 0)      mask = to_mask[b * M_ + kb * 64 + kk];
            else if (mode == 1) mask = band_mask[(((size_t)b * (NB_ - 4) + (qb - 2)) * 64 + row) * 192 + boff + kk];
            else                mask = fb * to_blocked[(b * NB_ + kb) * 64 + kk];
            s += (1.0f - mask) * NEGV;
            s_lds[row][kk] = s;
        }
        __syncthreads();

        // ---- online-softmax update (each of the 4 row-threads redundantly
        //      computes m/l; owns dims [wv*16, wv*16+16)) ----
        float bm0 = -INFINITY, bm1 = -INFINITY, bm2 = -INFINITY, bm3 = -INFINITY;
        #pragma unroll 4
        for (int kk = 0; kk < 64; kk += 4) {
            bm0 = fmaxf(bm0, s_lds[row][kk + 0]);
            bm1 = fmaxf(bm1, s_lds[row][kk + 1]);
            bm2 = fmaxf(bm2, s_lds[row][kk + 2]);
            bm3 = fmaxf(bm3, s_lds[row][kk + 3]);
        }
        const float bm = fmaxf(fmaxf(bm0, bm1), fmaxf(bm2, bm3));
        const float mnew = fmaxf(mrun, bm);
        const float f = __expf(mrun - mnew);   // exp(-inf)=0 on first tile
        lrun *= f;
        #pragma unroll
        for (int j = 0; j < 16; ++j) acc[j] *= f;

        const int c16 = wv * 16;
        #pragma unroll 4
        for (int kk = 0; kk < 64; ++kk) {
            const float p = __expf(s_lds[row][kk] - mnew);
            lrun += p;
            const float4* vp4 = (const float4*)&v_lds[kk][c16];  // wave-uniform -> broadcast
            #pragma unroll
            for (int j4 = 0; j4 < 4; ++j4) {
                float4 vv = vp4[j4];
                acc[j4 * 4 + 0] += p * vv.x;
                acc[j4 * 4 + 1] += p * vv.y;
                acc[j4 * 4 + 2] += p * vv.z;
                acc[j4 * 4 + 3] += p * vv.w;
            }
        }
        mrun = mnew;
        __syncthreads();
    }

    // ---- epilogue: normalize, from_mask, write transposed (B,M,H,D) ----
    const float fm  = from_mask[b * M_ + qb * 64 + row];
    const float sc  = fm / lrun;
    float* op = out + (((size_t)b * M_ + (size_t)qb * 64 + row) * H_ + h) * D_ + wv * 16;
    #pragma unroll
    for (int j4 = 0; j4 < 4; ++j4) {
        float4 o;
        o.x = acc[j4 * 4 + 0] * sc;
        o.y = acc[j4 * 4 + 1] * sc;
        o.z = acc[j4 * 4 + 2] * sc;
        o.w = acc[j4 * 4 + 3] * sc;
        *(float4*)(op + j4 * 4) = o;
    }
}

extern "C" void kernel_launch(void* const* d_in, const int* in_sizes, int n_in,
                              void* d_out, int out_size, void* d_ws, size_t ws_size,
                              hipStream_t stream) {
    const float* q  = (const float*)d_in[0];
    const float* k  = (const float*)d_in[1];
    const float* v  = (const float*)d_in[2];
    const float* bm = (const float*)d_in[3];
    const float* fm = (const float*)d_in[4];
    const float* tm = (const float*)d_in[5];
    const float* fb = (const float*)d_in[6];
    const float* tb = (const float*)d_in[7];
    const int*   ra = (const int*)d_in[8];
    float* o = (float*)d_out;

    dim3 grid(B_ * H_ * NB_);
    dim3 block(256);
    hipLaunchKernelGGL(bigbird_fp32, grid, block, 0, stream,
                       q, k, v, bm, fm, tm, fb, tb, ra, o);
}

// Round 2
// 502.500 us; speedup vs baseline: 3.9566x; 3.9566x over previous
//
#include <hip/hip_runtime.h>
#include <math.h>

// BigBird block-sparse attention, fp32 vector version, load-balanced.
// B=2 H=16 M=N=4096 D=64 WM=WN=64 R=3 nb=64.
// Edge q-blocks (0, 63) are full-attention (64 key-blocks): split into 8
// chunks of 8 key-blocks, each chunk a WG writing partial (acc,m,l) to d_ws;
// a combine kernel merges them. All WGs then do <=8 key-tiles.
constexpr int B_  = 2;
constexpr int H_  = 16;
constexpr int M_  = 4096;
constexpr int D_  = 64;
constexpr int NB_ = 64;
constexpr int R_  = 3;
constexpr float NEGV  = -10000.0f;
constexpr float SCALE = 0.125f;   // 1/sqrt(64)

constexpr int PER_BH = 62 + 16;             // 62 middle + 2 edges * 8 chunks
constexpr int PACC_OFF = 0;                                  // [BH][2][8][64][64]
constexpr int PM_OFF   = B_ * H_ * 2 * 8 * 64 * 64;          // [BH][2][8][64]
constexpr int PL_OFF   = PM_OFF + B_ * H_ * 2 * 8 * 64;

__global__ __launch_bounds__(256, 2)
void bigbird_main(const float* __restrict__ q,  const float* __restrict__ k,
                  const float* __restrict__ v,  const float* __restrict__ band_mask,
                  const float* __restrict__ from_mask, const float* __restrict__ to_mask,
                  const float* __restrict__ from_blocked, const float* __restrict__ to_blocked,
                  const int*   __restrict__ rand_attn,   float* __restrict__ out,
                  float* __restrict__ ws)
{
    __shared__ float k_lds[64][68];
    __shared__ float v_lds[64][68];
    __shared__ float s_lds[64][66];
    __shared__ int   s_kbl[8];
    __shared__ int   s_md[8];
    __shared__ int   s_boff[8];
    __shared__ int   s_nkb;

    const int wg  = blockIdx.x;
    const int bh  = wg / PER_BH;
    const int idx = wg % PER_BH;
    const int h   = bh % H_;
    const int b   = bh / H_;
    int qb, e = -1, c = 0;
    if (idx < 62)      { qb = idx + 1; }
    else if (idx < 70) { e = 0; c = idx - 62; qb = 0; }
    else               { e = 1; c = idx - 70; qb = NB_ - 1; }

    const int t   = threadIdx.x;
    const int row = t & 63;
    const int wv  = t >> 6;

    // ---- build the key-block list ----
    if (t == 0) {
        int n;
        if (e >= 0) {
            for (int j = 0; j < 8; ++j) { s_kbl[j] = c * 8 + j; s_md[j] = 0; s_boff[j] = 0; }
            n = 8;
        } else {
            const int l = qb - 1;
            const int* ra = rand_attn + ((b * H_ + h) * (NB_ - 2) + l) * R_;
            if (qb == 1) {
                const int base[4] = {0, 1, 2, NB_ - 1};
                for (int j = 0; j < 4; ++j) { s_kbl[j] = base[j]; s_md[j] = 0; s_boff[j] = 0; }
                for (int j = 0; j < R_; ++j) { s_kbl[4 + j] = ra[j]; s_md[4 + j] = 2; s_boff[4 + j] = 0; }
                n = 4 + R_;
            } else if (qb == NB_ - 2) {
                const int base[4] = {0, NB_ - 3, NB_ - 2, NB_ - 1};
                for (int j = 0; j < 4; ++j) { s_kbl[j] = base[j]; s_md[j] = 0; s_boff[j] = 0; }
                for (int j = 0; j < R_; ++j) { s_kbl[4 + j] = ra[j]; s_md[4 + j] = 2; s_boff[4 + j] = 0; }
                n = 4 + R_;
            } else {
                s_kbl[0] = 0;      s_md[0] = 0; s_boff[0] = 0;
                s_kbl[1] = qb - 1; s_md[1] = 1; s_boff[1] = 0;
                s_kbl[2] = qb;     s_md[2] = 1; s_boff[2] = 64;
                s_kbl[3] = qb + 1; s_md[3] = 1; s_boff[3] = 128;
                for (int j = 0; j < R_; ++j) { s_kbl[4 + j] = ra[j]; s_md[4 + j] = 2; s_boff[4 + j] = 0; }
                s_kbl[7] = NB_ - 1; s_md[7] = 0; s_boff[7] = 0;
                n = 8;
            }
        }
        s_nkb = n;
    }

    // ---- q row into registers ----
    float qr[64];
    {
        const float* qp = q + ((size_t)bh * M_ + (size_t)qb * 64 + row) * D_;
        #pragma unroll
        for (int j4 = 0; j4 < 16; ++j4) {
            float4 qv = *(const float4*)(qp + j4 * 4);
            qr[j4 * 4 + 0] = qv.x; qr[j4 * 4 + 1] = qv.y;
            qr[j4 * 4 + 2] = qv.z; qr[j4 * 4 + 3] = qv.w;
        }
    }

    __syncthreads();
    const int nkb = s_nkb;

    const float fb = from_blocked[(b * NB_ + qb) * 64 + row];

    float mrun = -INFINITY, lrun = 0.0f;
    float acc[16];
    #pragma unroll
    for (int j = 0; j < 16; ++j) acc[j] = 0.0f;

    for (int it = 0; it < nkb; ++it) {
        const int kb   = s_kbl[it];
        const int mode = s_md[it];
        const int boff = s_boff[it];

        {
            const float* kp = k + ((size_t)bh * M_ + (size_t)kb * 64) * D_;
            const float* vp = v + ((size_t)bh * M_ + (size_t)kb * 64) * D_;
            const int rr = t >> 2, cc = (t & 3) * 16;
            #pragma unroll
            for (int j4 = 0; j4 < 4; ++j4) {
                *(float4*)&k_lds[rr][cc + j4 * 4] = *(const float4*)(kp + rr * 64 + cc + j4 * 4);
                *(float4*)&v_lds[rr][cc + j4 * 4] = *(const float4*)(vp + rr * 64 + cc + j4 * 4);
            }
        }
        __syncthreads();

        #pragma unroll 2
        for (int jj = 0; jj < 16; ++jj) {
            const int kk = wv * 16 + jj;
            const float4* kp4 = (const float4*)&k_lds[kk][0];
            float s0 = 0.f, s1 = 0.f, s2 = 0.f, s3 = 0.f;
            #pragma unroll
            for (int d4 = 0; d4 < 16; ++d4) {
                float4 kv = kp4[d4];
                s0 += qr[d4 * 4 + 0] * kv.x;
                s1 += qr[d4 * 4 + 1] * kv.y;
                s2 += qr[d4 * 4 + 2] * kv.z;
                s3 += qr[d4 * 4 + 3] * kv.w;
            }
            float s = (s0 + s1) + (s2 + s3);
            s *= SCALE;
            float mask;
            if (mode == 0)      mask = to_mask[b * M_ + kb * 64 + kk];
            else if (mode == 1) mask = band_mask[(((size_t)b * (NB_ - 4) + (qb - 2)) * 64 + row) * 192 + boff + kk];
            else                mask = fb * to_blocked[(b * NB_ + kb) * 64 + kk];
            s += (1.0f - mask) * NEGV;
            s_lds[row][kk] = s;
        }
        __syncthreads();

        float bm0 = -INFINITY, bm1 = -INFINITY, bm2 = -INFINITY, bm3 = -INFINITY;
        #pragma unroll 4
        for (int kk = 0; kk < 64; kk += 4) {
            bm0 = fmaxf(bm0, s_lds[row][kk + 0]);
            bm1 = fmaxf(bm1, s_lds[row][kk + 1]);
            bm2 = fmaxf(bm2, s_lds[row][kk + 2]);
            bm3 = fmaxf(bm3, s_lds[row][kk + 3]);
        }
        const float bm = fmaxf(fmaxf(bm0, bm1), fmaxf(bm2, bm3));
        const float mnew = fmaxf(mrun, bm);
        const float f = __expf(mrun - mnew);
        lrun *= f;
        #pragma unroll
        for (int j = 0; j < 16; ++j) acc[j] *= f;

        const int c16 = wv * 16;
        #pragma unroll 4
        for (int kk = 0; kk < 64; ++kk) {
            const float p = __expf(s_lds[row][kk] - mnew);
            lrun += p;
            const float4* vp4 = (const float4*)&v_lds[kk][c16];
            #pragma unroll
            for (int j4 = 0; j4 < 4; ++j4) {
                float4 vv = vp4[j4];
                acc[j4 * 4 + 0] += p * vv.x;
                acc[j4 * 4 + 1] += p * vv.y;
                acc[j4 * 4 + 2] += p * vv.z;
                acc[j4 * 4 + 3] += p * vv.w;
            }
        }
        mrun = mnew;
        __syncthreads();
    }

    if (e < 0) {
        const float fm  = from_mask[b * M_ + qb * 64 + row];
        const float sc  = fm / lrun;
        float* op = out + (((size_t)b * M_ + (size_t)qb * 64 + row) * H_ + h) * D_ + wv * 16;
        #pragma unroll
        for (int j4 = 0; j4 < 4; ++j4) {
            float4 o;
            o.x = acc[j4 * 4 + 0] * sc; o.y = acc[j4 * 4 + 1] * sc;
            o.z = acc[j4 * 4 + 2] * sc; o.w = acc[j4 * 4 + 3] * sc;
            *(float4*)(op + j4 * 4) = o;
        }
    } else {
        const int pe = (bh * 2 + e) * 8 + c;
        float* pa = ws + PACC_OFF + ((size_t)pe * 64 + row) * 64 + wv * 16;
        #pragma unroll
        for (int j4 = 0; j4 < 4; ++j4) {
            float4 o;
            o.x = acc[j4 * 4 + 0]; o.y = acc[j4 * 4 + 1];
            o.z = acc[j4 * 4 + 2]; o.w = acc[j4 * 4 + 3];
            *(float4*)(pa + j4 * 4) = o;
        }
        if (wv == 0) {
            ws[PM_OFF + pe * 64 + row] = mrun;
            ws[PL_OFF + pe * 64 + row] = lrun;
        }
    }
}

// Combine the 8 partials for each edge q-block row.
__global__ __launch_bounds__(256)
void bigbird_combine(const float* __restrict__ ws, const float* __restrict__ from_mask,
                     float* __restrict__ out)
{
    const int g  = blockIdx.x;          // bh*2 + e
    const int e  = g & 1;
    const int bh = g >> 1;
    const int h  = bh % H_;
    const int b  = bh / H_;
    const int qb = e ? NB_ - 1 : 0;

    const int t  = threadIdx.x;
    const int r  = t >> 2;
    const int dq = (t & 3) * 16;

    float mc[8], lc[8];
    float m = -INFINITY;
    #pragma unroll
    for (int c = 0; c < 8; ++c) {
        mc[c] = ws[PM_OFF + (g * 8 + c) * 64 + r];
        lc[c] = ws[PL_OFF + (g * 8 + c) * 64 + r];
        m = fmaxf(m, mc[c]);
    }
    float l = 0.0f;
    float acc[16];
    #pragma unroll
    for (int j = 0; j < 16; ++j) acc[j] = 0.0f;
    #pragma unroll
    for (int c = 0; c < 8; ++c) {
        const float sc = __expf(mc[c] - m);
        l += lc[c] * sc;
        const float4* pa = (const float4*)(ws + PACC_OFF + ((size_t)(g * 8 + c) * 64 + r) * 64 + dq);
        #pragma unroll
        for (int j4 = 0; j4 < 4; ++j4) {
            float4 av = pa[j4];
            acc[j4 * 4 + 0] += sc * av.x;
            acc[j4 * 4 + 1] += sc * av.y;
            acc[j4 * 4 + 2] += sc * av.z;
            acc[j4 * 4 + 3] += sc * av.w;
        }
    }
    const float fm = from_mask[b * M_ + qb * 64 + r];
    const float s  = fm / l;
    float* op = out + (((size_t)b * M_ + (size_t)qb * 64 + r) * H_ + h) * D_ + dq;
    #pragma unroll
    for (int j4 = 0; j4 < 4; ++j4) {
        float4 o;
        o.x = acc[j4 * 4 + 0] * s; o.y = acc[j4 * 4 + 1] * s;
        o.z = acc[j4 * 4 + 2] * s; o.w = acc[j4 * 4 + 3] * s;
        *(float4*)(op + j4 * 4) = o;
    }
}

extern "C" void kernel_launch(void* const* d_in, const int* in_sizes, int n_in,
                              void* d_out, int out_size, void* d_ws, size_t ws_size,
                              hipStream_t stream) {
    const float* q  = (const float*)d_in[0];
    const float* k  = (const float*)d_in[1];
    const float* v  = (const float*)d_in[2];
    const float* bm = (const float*)d_in[3];
    const float* fm = (const float*)d_in[4];
    const float* tm = (const float*)d_in[5];
    const float* fb = (const float*)d_in[6];
    const float* tb = (const float*)d_in[7];
    const int*   ra = (const int*)d_in[8];
    float* o  = (float*)d_out;
    float* ws = (float*)d_ws;

    hipLaunchKernelGGL(bigbird_main, dim3(B_ * H_ * PER_BH), dim3(256), 0, stream,
                       q, k, v, bm, fm, tm, fb, tb, ra, o, ws);
    hipLaunchKernelGGL(bigbird_combine, dim3(B_ * H_ * 2), dim3(256), 0, stream,
                       ws, fm, o);
}

// Round 3
// 163.049 us; speedup vs baseline: 12.1939x; 3.0819x over previous
//
#include <hip/hip_runtime.h>
#include <math.h>

// BigBird block-sparse attention, bf16 MFMA version.
// B=2 H=16 M=N=4096 D=64 WM=WN=64 R=3 nb=64.
// Per WG: (b,h,qblock-or-edge-chunk), 256 thr = 4 waves, each wave owns 16 q rows.
// Swapped QK^T (S^T = K * Q^T) keeps softmax lane-local; P redistributed to the
// PV A-fragment layout via in-wave shuffles.
constexpr int B_  = 2;
constexpr int H_  = 16;
constexpr int M_  = 4096;
constexpr int NB_ = 64;
constexpr int R_  = 3;
constexpr float NEGV  = -10000.0f;
constexpr float SCALE = 0.125f;   // 1/sqrt(64)

constexpr int PER_BH = 62 + 16;             // 62 middle + 2 edges * 8 chunks
constexpr int PACC_OFF = 0;                                  // [BH][2][8][64][64]
constexpr int PM_OFF   = B_ * H_ * 2 * 8 * 64 * 64;          // [BH][2][8][64]
constexpr int PL_OFF   = PM_OFF + B_ * H_ * 2 * 8 * 64;

typedef short bf16x8 __attribute__((ext_vector_type(8)));   // 8 bf16 in 4 VGPRs
typedef float f32x4  __attribute__((ext_vector_type(4)));

__device__ __forceinline__ short bf16s(float x) {
    return __builtin_bit_cast(short, (__bf16)x);
}
__device__ __forceinline__ unsigned pack_bf16(float a, float b) {
    unsigned short ul = __builtin_bit_cast(unsigned short, (__bf16)a);
    unsigned short uh = __builtin_bit_cast(unsigned short, (__bf16)b);
    return (unsigned)ul | ((unsigned)uh << 16);
}

__global__ __launch_bounds__(256, 3)
void bigbird_mfma(const float* __restrict__ q,  const float* __restrict__ k,
                  const float* __restrict__ v,  const float* __restrict__ band_mask,
                  const float* __restrict__ from_mask, const float* __restrict__ to_mask,
                  const float* __restrict__ from_blocked, const float* __restrict__ to_blocked,
                  const int*   __restrict__ rand_attn,   float* __restrict__ out,
                  float* __restrict__ ws)
{
    // K staged in A-fragment-linear order: slot (f*2+dh)*64 + l holds 16B:
    //   K[16f + (l&15)][32dh + (l>>4)*8 + j], j=0..7   (bf16)
    // V staged in B-fragment-linear order: slot (nf*2+kh)*64 + l holds:
    //   V[32kh + (l>>4)*8 + j][nf*16 + (l&15)], j=0..7 (bf16)
    __shared__ int4 kf[8][64];   // 8 KB
    __shared__ int4 vf[8][64];   // 8 KB
    __shared__ int  s_kbl[8], s_md[8], s_boff[8];
    __shared__ int  s_nkb;

    const int wg  = blockIdx.x;
    const int bh  = wg / PER_BH;
    const int idx = wg % PER_BH;
    const int h   = bh % H_;
    const int b   = bh / H_;
    int qb, e = -1, ch = 0;
    if (idx < 62)      { qb = idx + 1; }
    else if (idx < 70) { e = 0; ch = idx - 62; qb = 0; }
    else               { e = 1; ch = idx - 70; qb = NB_ - 1; }

    const int t  = threadIdx.x;
    const int l  = t & 63;
    const int w  = t >> 6;
    const int c  = l & 15;      // q index within wave strip
    const int hh = l >> 4;      // lane quarter

    if (t == 0) {
        int n;
        if (e >= 0) {
            for (int j = 0; j < 8; ++j) { s_kbl[j] = ch * 8 + j; s_md[j] = 0; s_boff[j] = 0; }
            n = 8;
        } else {
            const int* ra = rand_attn + ((b * H_ + h) * (NB_ - 2) + (qb - 1)) * R_;
            if (qb == 1) {
                const int base[4] = {0, 1, 2, NB_ - 1};
                for (int j = 0; j < 4; ++j) { s_kbl[j] = base[j]; s_md[j] = 0; s_boff[j] = 0; }
                for (int j = 0; j < R_; ++j) { s_kbl[4 + j] = ra[j]; s_md[4 + j] = 2; s_boff[4 + j] = 0; }
                n = 4 + R_;
            } else if (qb == NB_ - 2) {
                const int base[4] = {0, NB_ - 3, NB_ - 2, NB_ - 1};
                for (int j = 0; j < 4; ++j) { s_kbl[j] = base[j]; s_md[j] = 0; s_boff[j] = 0; }
                for (int j = 0; j < R_; ++j) { s_kbl[4 + j] = ra[j]; s_md[4 + j] = 2; s_boff[4 + j] = 0; }
                n = 4 + R_;
            } else {
                s_kbl[0] = 0;      s_md[0] = 0; s_boff[0] = 0;
                s_kbl[1] = qb - 1; s_md[1] = 1; s_boff[1] = 0;
                s_kbl[2] = qb;     s_md[2] = 1; s_boff[2] = 64;
                s_kbl[3] = qb + 1; s_md[3] = 1; s_boff[3] = 128;
                for (int j = 0; j < R_; ++j) { s_kbl[4 + j] = ra[j]; s_md[4 + j] = 2; s_boff[4 + j] = 0; }
                s_kbl[7] = NB_ - 1; s_md[7] = 0; s_boff[7] = 0;
                n = 8;
            }
        }
        s_nkb = n;
    }

    // staging geometry: thread owns row rr, 16 cols starting cc4*16
    const int rr  = t >> 2;
    const int cc4 = t & 3;
    const float* kbase = k + ((size_t)bh * M_ + rr) * 64 + cc4 * 16;
    const float* vbase = v + ((size_t)bh * M_ + rr) * 64 + cc4 * 16;

    __syncthreads();
    const int nkb = s_nkb;

    // ---- Q B-fragments (held all kernel): lane holds Q[q0w + c][32dh + hh*8 + j]
    bf16x8 qf[2];
    {
        const float* qp = q + ((size_t)bh * M_ + (size_t)qb * 64 + w * 16 + c) * 64 + hh * 8;
        #pragma unroll
        for (int dh = 0; dh < 2; ++dh) {
            float4 a0 = *(const float4*)(qp + dh * 32);
            float4 a1 = *(const float4*)(qp + dh * 32 + 4);
            bf16x8 qv;
            qv[0] = bf16s(a0.x); qv[1] = bf16s(a0.y); qv[2] = bf16s(a0.z); qv[3] = bf16s(a0.w);
            qv[4] = bf16s(a1.x); qv[5] = bf16s(a1.y); qv[6] = bf16s(a1.z); qv[7] = bf16s(a1.w);
            qf[dh] = qv;
        }
    }

    const float fbv = from_blocked[(b * NB_ + qb) * 64 + (w * 16 + c)];

    float mrun = -INFINITY, lrun = 0.0f;
    f32x4 O[4];
    #pragma unroll
    for (int nf = 0; nf < 4; ++nf) { O[nf][0] = 0.f; O[nf][1] = 0.f; O[nf][2] = 0.f; O[nf][3] = 0.f; }

    // ---- prefetch tile 0 into registers
    float4 kr0, kr1, kr2, kr3, vr0, vr1, vr2, vr3;
    {
        const float4* kp4 = (const float4*)(kbase + (size_t)s_kbl[0] * 4096);
        const float4* vp4 = (const float4*)(vbase + (size_t)s_kbl[0] * 4096);
        kr0 = kp4[0]; kr1 = kp4[1]; kr2 = kp4[2]; kr3 = kp4[3];
        vr0 = vp4[0]; vr1 = vp4[1]; vr2 = vp4[2]; vr3 = vp4[3];
    }

    for (int it = 0; it < nkb; ++it) {
        __syncthreads();   // previous tile fully consumed

        // ---- write prefetched tile into fragment-linear LDS (cvt to bf16)
        {
            float kfl[16];
            kfl[0]=kr0.x; kfl[1]=kr0.y; kfl[2]=kr0.z; kfl[3]=kr0.w;
            kfl[4]=kr1.x; kfl[5]=kr1.y; kfl[6]=kr1.z; kfl[7]=kr1.w;
            kfl[8]=kr2.x; kfl[9]=kr2.y; kfl[10]=kr2.z; kfl[11]=kr2.w;
            kfl[12]=kr3.x; kfl[13]=kr3.y; kfl[14]=kr3.z; kfl[15]=kr3.w;
            bf16x8 o0, o1;
            #pragma unroll
            for (int j = 0; j < 8; ++j) { o0[j] = bf16s(kfl[j]); o1[j] = bf16s(kfl[8 + j]); }
            const int f = rr >> 4, dh = cc4 >> 1, r15 = rr & 15, g0 = (cc4 & 1) * 2;
            kf[f * 2 + dh][g0 * 16 + r15]       = __builtin_bit_cast(int4, o0);
            kf[f * 2 + dh][(g0 + 1) * 16 + r15] = __builtin_bit_cast(int4, o1);

            float vfl[16];
            vfl[0]=vr0.x; vfl[1]=vr0.y; vfl[2]=vr0.z; vfl[3]=vr0.w;
            vfl[4]=vr1.x; vfl[5]=vr1.y; vfl[6]=vr1.z; vfl[7]=vr1.w;
            vfl[8]=vr2.x; vfl[9]=vr2.y; vfl[10]=vr2.z; vfl[11]=vr2.w;
            vfl[12]=vr3.x; vfl[13]=vr3.y; vfl[14]=vr3.z; vfl[15]=vr3.w;
            short* vb = (short*)vf;
            const int kh = rr >> 5, oct = (rr & 31) >> 3, jj = rr & 7;
            const int base16 = (cc4 * 2 + kh) * 64 + oct * 16;
            #pragma unroll
            for (int i = 0; i < 16; ++i) vb[(base16 + i) * 8 + jj] = bf16s(vfl[i]);
        }
        __syncthreads();

        const int kb = s_kbl[it], mode = s_md[it], boff = s_boff[it];

        // ---- prefetch next tile (overlaps MFMA/softmax below)
        if (it + 1 < nkb) {
            const float4* kp4 = (const float4*)(kbase + (size_t)s_kbl[it + 1] * 4096);
            const float4* vp4 = (const float4*)(vbase + (size_t)s_kbl[it + 1] * 4096);
            kr0 = kp4[0]; kr1 = kp4[1]; kr2 = kp4[2]; kr3 = kp4[3];
            vr0 = vp4[0]; vr1 = vp4[1]; vr2 = vp4[2]; vr3 = vp4[3];
        }

        // ---- S^T = K * Q^T : lane holds S[q = c][k = 16f + 4hh + r]
        f32x4 sf[4];
        #pragma unroll
        for (int f = 0; f < 4; ++f) { sf[f][0]=0.f; sf[f][1]=0.f; sf[f][2]=0.f; sf[f][3]=0.f; }
        #pragma unroll
        for (int f = 0; f < 4; ++f) {
            sf[f] = __builtin_amdgcn_mfma_f32_16x16x32_bf16(
                        __builtin_bit_cast(bf16x8, kf[f * 2 + 0][l]), qf[0], sf[f], 0, 0, 0);
            sf[f] = __builtin_amdgcn_mfma_f32_16x16x32_bf16(
                        __builtin_bit_cast(bf16x8, kf[f * 2 + 1][l]), qf[1], sf[f], 0, 0, 0);
        }

        // ---- scale + mask + online softmax (lane-local + 2 shfl_xor)
        float p[4][4];
        float tmax = -INFINITY;
        #pragma unroll
        for (int f = 0; f < 4; ++f) {
            #pragma unroll
            for (int r = 0; r < 4; ++r) {
                const int klocal = 16 * f + 4 * hh + r;
                float mask;
                if (mode == 0)      mask = to_mask[b * M_ + kb * 64 + klocal];
                else if (mode == 1) mask = band_mask[(((size_t)b * (NB_ - 4) + (qb - 2)) * 64 + (w * 16 + c)) * 192 + boff + klocal];
                else                mask = fbv * to_blocked[(b * NB_ + kb) * 64 + klocal];
                const float s = sf[f][r] * SCALE + (1.0f - mask) * NEGV;
                p[f][r] = s;
                tmax = fmaxf(tmax, s);
            }
        }
        tmax = fmaxf(tmax, __shfl_xor(tmax, 16));
        tmax = fmaxf(tmax, __shfl_xor(tmax, 32));
        const float mnew = fmaxf(mrun, tmax);
        const float fs = __expf(mrun - mnew);   // 0 on first tile
        float sum = 0.0f;
        #pragma unroll
        for (int f = 0; f < 4; ++f) {
            #pragma unroll
            for (int r = 0; r < 4; ++r) { p[f][r] = __expf(p[f][r] - mnew); sum += p[f][r]; }
        }
        sum += __shfl_xor(sum, 16);
        sum += __shfl_xor(sum, 32);
        lrun = lrun * fs + sum;
        mrun = mnew;

        // ---- rescale O (rows are q = 4hh + r -> fetch fs from lane 4hh+r)
        const float fr0 = __shfl(fs, hh * 4 + 0);
        const float fr1 = __shfl(fs, hh * 4 + 1);
        const float fr2 = __shfl(fs, hh * 4 + 2);
        const float fr3 = __shfl(fs, hh * 4 + 3);
        #pragma unroll
        for (int nf = 0; nf < 4; ++nf) {
            O[nf][0] *= fr0; O[nf][1] *= fr1; O[nf][2] *= fr2; O[nf][3] *= fr3;
        }

        // ---- P -> bf16, redistribute to PV A-frag layout (in-wave shuffles)
        unsigned pks[4][2];
        #pragma unroll
        for (int f = 0; f < 4; ++f) {
            pks[f][0] = pack_bf16(p[f][0], p[f][1]);
            pks[f][1] = pack_bf16(p[f][2], p[f][3]);
        }
        #pragma unroll
        for (int kh = 0; kh < 2; ++kh) {
            unsigned ad[4];
            #pragma unroll
            for (int wq = 0; wq < 4; ++wq) {
                const int pos = wq >> 1, ww = wq & 1;
                const int src = c + 16 * ((2 * hh + pos) & 3);
                const unsigned x = (unsigned)__shfl((int)pks[2 * kh][ww], src);
                const unsigned y = (unsigned)__shfl((int)pks[2 * kh + 1][ww], src);
                ad[wq] = (hh & 2) ? y : x;
            }
            const uint4 adv = make_uint4(ad[0], ad[1], ad[2], ad[3]);
            const bf16x8 pa = __builtin_bit_cast(bf16x8, adv);
            #pragma unroll
            for (int nf = 0; nf < 4; ++nf) {
                O[nf] = __builtin_amdgcn_mfma_f32_16x16x32_bf16(
                            pa, __builtin_bit_cast(bf16x8, vf[nf * 2 + kh][l]), O[nf], 0, 0, 0);
            }
        }
    }

    // ---- epilogue: O rows are q_local = w*16 + 4hh + r, cols d = nf*16 + c
    if (e < 0) {
        #pragma unroll
        for (int r = 0; r < 4; ++r) {
            const float lr  = __shfl(lrun, hh * 4 + r);
            const int   qg  = qb * 64 + w * 16 + hh * 4 + r;
            const float fmv = from_mask[b * M_ + qg];
            const float scl = fmv / lr;
            float* op = out + (((size_t)b * M_ + qg) * H_ + h) * 64 + c;
            #pragma unroll
            for (int nf = 0; nf < 4; ++nf) op[nf * 16] = O[nf][r] * scl;
        }
    } else {
        const int pe = (bh * 2 + e) * 8 + ch;
        #pragma unroll
        for (int r = 0; r < 4; ++r) {
            const int qlocal = w * 16 + hh * 4 + r;
            float* pa = ws + PACC_OFF + ((size_t)pe * 64 + qlocal) * 64 + c;
            #pragma unroll
            for (int nf = 0; nf < 4; ++nf) pa[nf * 16] = O[nf][r];
        }
        if (hh == 0) {
            ws[PM_OFF + pe * 64 + w * 16 + c] = mrun;
            ws[PL_OFF + pe * 64 + w * 16 + c] = lrun;
        }
    }
}

// Combine the 8 partials for each edge q-block row.
__global__ __launch_bounds__(256)
void bigbird_combine(const float* __restrict__ ws, const float* __restrict__ from_mask,
                     float* __restrict__ out)
{
    const int g  = blockIdx.x;          // bh*2 + e
    const int e  = g & 1;
    const int bh = g >> 1;
    const int h  = bh % H_;
    const int b  = bh / H_;
    const int qb = e ? NB_ - 1 : 0;

    const int t  = threadIdx.x;
    const int r  = t >> 2;
    const int dq = (t & 3) * 16;

    float mc[8], lc[8];
    float m = -INFINITY;
    #pragma unroll
    for (int c = 0; c < 8; ++c) {
        mc[c] = ws[PM_OFF + (g * 8 + c) * 64 + r];
        lc[c] = ws[PL_OFF + (g * 8 + c) * 64 + r];
        m = fmaxf(m, mc[c]);
    }
    float l = 0.0f;
    float acc[16];
    #pragma unroll
    for (int j = 0; j < 16; ++j) acc[j] = 0.0f;
    #pragma unroll
    for (int c = 0; c < 8; ++c) {
        const float sc = __expf(mc[c] - m);
        l += lc[c] * sc;
        const float4* pa = (const float4*)(ws + PACC_OFF + ((size_t)(g * 8 + c) * 64 + r) * 64 + dq);
        #pragma unroll
        for (int j4 = 0; j4 < 4; ++j4) {
            float4 av = pa[j4];
            acc[j4 * 4 + 0] += sc * av.x;
            acc[j4 * 4 + 1] += sc * av.y;
            acc[j4 * 4 + 2] += sc * av.z;
            acc[j4 * 4 + 3] += sc * av.w;
        }
    }
    const float fm = from_mask[b * M_ + qb * 64 + r];
    const float s  = fm / l;
    float* op = out + (((size_t)b * M_ + qb * 64 + r) * H_ + h) * 64 + dq;
    #pragma unroll
    for (int j4 = 0; j4 < 4; ++j4) {
        float4 o;
        o.x = acc[j4 * 4 + 0] * s; o.y = acc[j4 * 4 + 1] * s;
        o.z = acc[j4 * 4 + 2] * s; o.w = acc[j4 * 4 + 3] * s;
        *(float4*)(op + j4 * 4) = o;
    }
}

extern "C" void kernel_launch(void* const* d_in, const int* in_sizes, int n_in,
                              void* d_out, int out_size, void* d_ws, size_t ws_size,
                              hipStream_t stream) {
    const float* q  = (const float*)d_in[0];
    const float* k  = (const float*)d_in[1];
    const float* v  = (const float*)d_in[2];
    const float* bm = (const float*)d_in[3];
    const float* fm = (const float*)d_in[4];
    const float* tm = (const float*)d_in[5];
    const float* fb = (const float*)d_in[6];
    const float* tb = (const float*)d_in[7];
    const int*   ra = (const int*)d_in[8];
    float* o  = (float*)d_out;
    float* ws = (float*)d_ws;

    hipLaunchKernelGGL(bigbird_mfma, dim3(B_ * H_ * PER_BH), dim3(256), 0, stream,
                       q, k, v, bm, fm, tm, fb, tb, ra, o, ws);
    hipLaunchKernelGGL(bigbird_combine, dim3(B_ * H_ * 2), dim3(256), 0, stream,
                       ws, fm, o);
}